// Round 5
// baseline (73.030 us; speedup 1.0000x reference)
//
#include <hip/hip_runtime.h>
#include <hip/hip_bf16.h>

// Hopf oscillator scan: B=32, T=1000, D=512. One thread per (b,d) chain.
// 256 waves = 1 wave/CU, latency-bound; per-wave outstanding-vmem queue
// caps at ~16 ops (measured R1/R2: in-flight bytes pin at ~3.6KB with
// scalar loads no matter how many are clustered). Fix: make every vmem op
// a dwordx4 via wave-cooperative LDS transpose -> 16 ops = 16KB in flight.
// Block = 1 wave: no __syncthreads (would drain vmcnt); same-wave DS is
// in-order, ordering pinned with lgkmcnt(0) + sched_barrier(0).

#define B 32
#define T 1000
#define D 512
#define DTc 0.001f
#define K_IN 0.005f               // INPUT_SCALER * DT
#define TWO_PI 6.283185307179586f
#define U 20                      // steps per body
#define NB (T / U)                // 50 bodies
#define NOPS (U / 4)              // 5 float4 ops per array per body

typedef float v4f __attribute__((ext_vector_type(4)));

#define LGKM0() asm volatile("s_waitcnt lgkmcnt(0)" ::: "memory")
#define SCHEDB() __builtin_amdgcn_sched_barrier(0)

__global__ __launch_bounds__(64, 1) void hopf_scan(
    const float* __restrict__ Xr, const float* __restrict__ Xi,
    const float* __restrict__ om,
    float* __restrict__ zr, float* __restrict__ zi) {
    const int i = threadIdx.x;            // lane 0..63
    const int bb = blockIdx.x;            // 0..255
    const int b = bb >> 3;
    const int dblk = (bb & 7) << 6;       // 64-d block
    const int ts = i >> 4;                // 0..3  (sub-step within a load op)
    const int dq = (i & 15) << 2;         // 0..60 (d quad within block)

    __shared__ __align__(16) float INr[2][U][64];
    __shared__ __align__(16) float INi[2][U][64];
    __shared__ __align__(16) float OUTr[U][64];
    __shared__ __align__(16) float OUTi[U][64];

    const size_t blkoff = (size_t)b * (T * D) + dblk;
    const float* __restrict__ xr_blk = Xr + blkoff;
    const float* __restrict__ xi_blk = Xi + blkoff;
    float* __restrict__ zr_blk = zr + blkoff;
    float* __restrict__ zi_blk = zi + blkoff;

    const float od = (om[dblk + i] * 10.0f + 0.1f) * TWO_PI * DTc;

    float r = 1.0f, phi = 0.0f, c = 1.0f, s = 0.0f;

    v4f Ar[NOPS], Ai[NOPS], Br[NOPS], Bi[NOPS];

    // issue: wave-cooperative float4 loads; op k covers steps t0+4k..t0+4k+3
    auto issue = [&](int t0, v4f (&vr)[NOPS], v4f (&vi)[NOPS]) {
#pragma unroll
        for (int k = 0; k < NOPS; ++k) {
            const size_t off = (size_t)(t0 + 4 * k + ts) * D + dq;
            vr[k] = *reinterpret_cast<const v4f*>(xr_blk + off);
            vi[k] = *reinterpret_cast<const v4f*>(xi_blk + off);
        }
    };
    auto stage = [&](int p, const v4f (&vr)[NOPS], const v4f (&vi)[NOPS]) {
#pragma unroll
        for (int k = 0; k < NOPS; ++k) {
            *reinterpret_cast<v4f*>(&INr[p][4 * k + ts][dq]) = vr[k];
            *reinterpret_cast<v4f*>(&INi[p][4 * k + ts][dq]) = vi[k];
        }
    };
    auto compute = [&](int p) {
#pragma unroll
        for (int t = 0; t < U; ++t) {
            const float xr = INr[p][t][i];
            const float xi = INi[p][t][i];
            r = r + ((1.0f - r * r) * r) * DTc + K_IN * xr * c;
            phi = phi + od - K_IN * xi * s;
            s = __sinf(phi);
            c = __cosf(phi);
            OUTr[t][i] = r * c;
            OUTi[t][i] = r * s;
        }
    };
    auto drain = [&](int t0) {
#pragma unroll
        for (int k = 0; k < NOPS; ++k) {
            const size_t off = (size_t)(t0 + 4 * k + ts) * D + dq;
            const v4f vr = *reinterpret_cast<const v4f*>(&OUTr[4 * k + ts][dq]);
            const v4f vi = *reinterpret_cast<const v4f*>(&OUTi[4 * k + ts][dq]);
            __builtin_nontemporal_store(vr, reinterpret_cast<v4f*>(zr_blk + off));
            __builtin_nontemporal_store(vi, reinterpret_cast<v4f*>(zi_blk + off));
        }
    };

    // 2-deep prologue
    issue(0, Ar, Ai);
    issue(U, Br, Bi);

    // main loop: iteration handles bodies n, n+1; issues loads n+2, n+3
    for (int n = 0; n < NB - 2; n += 2) {
        SCHEDB();
        stage(0, Ar, Ai);                 // waits on body-n loads (oldest)
        LGKM0(); SCHEDB();
        issue((n + 2) * U, Ar, Ai);       // refill A two bodies ahead
        SCHEDB();
        compute(0);
        LGKM0(); SCHEDB();
        drain(n * U);
        SCHEDB();
        stage(1, Br, Bi);
        LGKM0(); SCHEDB();
        issue((n + 3) * U, Br, Bi);
        SCHEDB();
        compute(1);
        LGKM0(); SCHEDB();
        drain((n + 1) * U);
        SCHEDB();
    }

    // epilogue: bodies NB-2 (in A) and NB-1 (in B), no further loads
    stage(0, Ar, Ai);
    LGKM0(); SCHEDB();
    compute(0);
    LGKM0(); SCHEDB();
    drain((NB - 2) * U);
    SCHEDB();
    stage(1, Br, Bi);
    LGKM0(); SCHEDB();
    compute(1);
    LGKM0(); SCHEDB();
    drain((NB - 1) * U);
}

extern "C" void kernel_launch(void* const* d_in, const int* in_sizes, int n_in,
                              void* d_out, int out_size, void* d_ws, size_t ws_size,
                              hipStream_t stream) {
    const float* Xr = (const float*)d_in[0];
    const float* Xi = (const float*)d_in[1];
    const float* om = (const float*)d_in[2];
    float* zr = (float*)d_out;
    float* zi = zr + (size_t)B * T * D;   // tuple output 2, flat-concatenated

    hopf_scan<<<dim3(B * D / 64), dim3(64), 0, stream>>>(Xr, Xi, om, zr, zi);
}

// Round 6
// 70.970 us; speedup vs baseline: 1.0290x; 1.0290x over previous
//
#include <hip/hip_runtime.h>
#include <hip/hip_bf16.h>

// Hopf oscillator scan: B=32, T=1000, D=512. One thread per (b,d) chain.
// 256 waves = 1 wave/CU, latency-bound. Wave-cooperative dwordx4 loads +
// LDS transpose raise in-flight bytes per vmem op. Single wave per block:
// no __syncthreads (would drain vmcnt). NO explicit waitcnt asm — R4 showed
// the "memory" clobber forces conservative vmcnt(0) drains; the compiler's
// own counted vmcnt/lgkmcnt insertion handles all same-wave dependencies.
// sched_barrier(0) only pins phase ORDER (no wait semantics).

#define B 32
#define T 1000
#define D 512
#define DTc 0.001f
#define K_IN 0.005f               // INPUT_SCALER * DT
#define TWO_PI 6.283185307179586f
#define U 20                      // steps per body
#define NB (T / U)                // 50 bodies
#define NOPS (U / 4)              // 5 float4 ops per array per body

typedef float v4f __attribute__((ext_vector_type(4)));

#define SCHEDB() __builtin_amdgcn_sched_barrier(0)

__global__ __launch_bounds__(64, 1) void hopf_scan(
    const float* __restrict__ Xr, const float* __restrict__ Xi,
    const float* __restrict__ om,
    float* __restrict__ zr, float* __restrict__ zi) {
    const int i = threadIdx.x;            // lane 0..63
    const int bb = blockIdx.x;            // 0..255
    const int b = bb >> 3;
    const int dblk = (bb & 7) << 6;       // 64-d block
    const int ts = i >> 4;                // 0..3  (sub-step within a load op)
    const int dq = (i & 15) << 2;         // 0..60 (d quad within block)

    __shared__ __align__(16) float INr[2][U][64];
    __shared__ __align__(16) float INi[2][U][64];
    __shared__ __align__(16) float OUTr[U][64];
    __shared__ __align__(16) float OUTi[U][64];

    const size_t blkoff = (size_t)b * (T * D) + dblk;
    const float* __restrict__ xr_blk = Xr + blkoff;
    const float* __restrict__ xi_blk = Xi + blkoff;
    float* __restrict__ zr_blk = zr + blkoff;
    float* __restrict__ zi_blk = zi + blkoff;

    const float od = (om[dblk + i] * 10.0f + 0.1f) * TWO_PI * DTc;

    float r = 1.0f, phi = 0.0f, c = 1.0f, s = 0.0f;

    v4f Ar[NOPS], Ai[NOPS], Br[NOPS], Bi[NOPS];

    // wave-cooperative float4 loads; op k covers steps t0+4k..t0+4k+3
    auto issue = [&](int t0, v4f (&vr)[NOPS], v4f (&vi)[NOPS]) {
#pragma unroll
        for (int k = 0; k < NOPS; ++k) {
            const size_t off = (size_t)(t0 + 4 * k + ts) * D + dq;
            vr[k] = *reinterpret_cast<const v4f*>(xr_blk + off);
            vi[k] = *reinterpret_cast<const v4f*>(xi_blk + off);
        }
    };
    auto stage = [&](int p, const v4f (&vr)[NOPS], const v4f (&vi)[NOPS]) {
#pragma unroll
        for (int k = 0; k < NOPS; ++k) {
            *reinterpret_cast<v4f*>(&INr[p][4 * k + ts][dq]) = vr[k];
            *reinterpret_cast<v4f*>(&INi[p][4 * k + ts][dq]) = vi[k];
        }
    };
    auto compute = [&](int p) {
#pragma unroll
        for (int t = 0; t < U; ++t) {
            const float xr = INr[p][t][i];
            const float xi = INi[p][t][i];
            r = r + ((1.0f - r * r) * r) * DTc + K_IN * xr * c;
            phi = phi + od - K_IN * xi * s;
            s = __sinf(phi);
            c = __cosf(phi);
            OUTr[t][i] = r * c;
            OUTi[t][i] = r * s;
        }
    };
    auto drain = [&](int t0) {
#pragma unroll
        for (int k = 0; k < NOPS; ++k) {
            const size_t off = (size_t)(t0 + 4 * k + ts) * D + dq;
            const v4f vr = *reinterpret_cast<const v4f*>(&OUTr[4 * k + ts][dq]);
            const v4f vi = *reinterpret_cast<const v4f*>(&OUTi[4 * k + ts][dq]);
            __builtin_nontemporal_store(vr, reinterpret_cast<v4f*>(zr_blk + off));
            __builtin_nontemporal_store(vi, reinterpret_cast<v4f*>(zi_blk + off));
        }
    };

    // 2-deep prologue
    issue(0, Ar, Ai);
    issue(U, Br, Bi);

    // main loop: iteration handles bodies n, n+1; issues loads n+2, n+3
    for (int n = 0; n < NB - 2; n += 2) {
        SCHEDB();
        stage(0, Ar, Ai);                 // compiler: counted vmcnt for A only
        SCHEDB();
        issue((n + 2) * U, Ar, Ai);       // refill A two bodies ahead
        SCHEDB();
        compute(0);                       // counted lgkmcnt per ds_read
        SCHEDB();
        drain(n * U);
        SCHEDB();
        stage(1, Br, Bi);
        SCHEDB();
        issue((n + 3) * U, Br, Bi);
        SCHEDB();
        compute(1);
        SCHEDB();
        drain((n + 1) * U);
        SCHEDB();
    }

    // epilogue: bodies NB-2 (in A) and NB-1 (in B), no further loads
    stage(0, Ar, Ai);
    compute(0);
    drain((NB - 2) * U);
    stage(1, Br, Bi);
    compute(1);
    drain((NB - 1) * U);
}

extern "C" void kernel_launch(void* const* d_in, const int* in_sizes, int n_in,
                              void* d_out, int out_size, void* d_ws, size_t ws_size,
                              hipStream_t stream) {
    const float* Xr = (const float*)d_in[0];
    const float* Xi = (const float*)d_in[1];
    const float* om = (const float*)d_in[2];
    float* zr = (float*)d_out;
    float* zi = zr + (size_t)B * T * D;   // tuple output 2, flat-concatenated

    hopf_scan<<<dim3(B * D / 64), dim3(64), 0, stream>>>(Xr, Xi, om, zr, zi);
}

// Round 7
// 49.592 us; speedup vs baseline: 1.4726x; 1.4311x over previous
//
#include <hip/hip_runtime.h>
#include <hip/hip_bf16.h>

// Hopf oscillator scan: B=32, T=1000, D=512.
// Producer/consumer wave specialization, 256 blocks x 128 threads (2 waves):
//   wave 0 (consumer): pure LDS+VALU recurrence, never touches vmem.
//   wave 1 (producer): global_load_lds (dwordx4) into 4-deep IN ring,
//                      drains OUT (b128 LDS read -> nontemporal x4 store).
// Raw s_barrier per body; producer uses hand-counted vmcnt(N) so 2-3 bodies
// of loads stay in flight across barriers (N values derived by exact FIFO
// simulation of the vmem queue; see table below). Consumer seals OUT with an
// lgkm-only waitcnt (0xC07F: vmcnt=63 unconstrained, expcnt=7, lgkm=0).

#define B 32
#define T 1000
#define D 512
#define DTc 0.001f
#define K_IN 0.005f               // INPUT_SCALER * DT
#define TWO_PI 6.283185307179586f
#define U 20                      // steps per body
#define NB (T / U)                // 50 bodies
#define NOPS (U / 4)              // 5 glds/drain ops per array per body

typedef float v4f __attribute__((ext_vector_type(4)));
typedef const __attribute__((address_space(1))) float gfloat;
typedef __attribute__((address_space(3))) float lfloat;

#define SCHEDB() __builtin_amdgcn_sched_barrier(0)
#define BAR()    __builtin_amdgcn_s_barrier()
// s_waitcnt simm16 (gfx9): [3:0]=vmcnt lo, [6:4]=expcnt, [11:8]=lgkmcnt, [15:14]=vmcnt hi
#define W_LGKM0  0xC07F   // lgkmcnt(0) only
#define W_VM20   0x4F74   // vmcnt(20) only
#define W_VM30   0x4F7E   // vmcnt(30) only
#define W_VM40   0x8F78   // vmcnt(40) only

__global__ __launch_bounds__(128, 1) void hopf_scan(
    const float* __restrict__ Xr, const float* __restrict__ Xi,
    const float* __restrict__ om,
    float* __restrict__ zr, float* __restrict__ zi) {
    const int tid = threadIdx.x;
    const int bb = blockIdx.x;            // 0..255
    const int b = bb >> 3;
    const int dblk = (bb & 7) << 6;       // 64-d block
    const size_t blkoff = (size_t)b * (T * D) + dblk;

    __shared__ __align__(16) float INr[4][U][64];   // 4-deep input ring
    __shared__ __align__(16) float INi[4][U][64];
    __shared__ __align__(16) float OUTr[2][U][64];  // double-buffered output
    __shared__ __align__(16) float OUTi[2][U][64];

    if (tid < 64) {
        // ---------------- consumer wave: LDS + VALU only ----------------
        const int i = tid;
        const float od = (om[dblk + i] * 10.0f + 0.1f) * TWO_PI * DTc;
        float r = 1.0f, phi = 0.0f, c = 1.0f, s = 0.0f;

        BAR();                            // body 0 staged by producer
        for (int n = 0; n < NB; ++n) {
            const int ib = n & 3, ob = n & 1;
#pragma unroll
            for (int t = 0; t < U; ++t) {
                const float xr = INr[ib][t][i];
                const float xi = INi[ib][t][i];
                r = r + ((1.0f - r * r) * r) * DTc + K_IN * xr * c;
                phi = phi + od - K_IN * xi * s;
                s = __sinf(phi);
                c = __cosf(phi);
                OUTr[ob][t][i] = r * c;
                OUTi[ob][t][i] = r * s;
            }
            __builtin_amdgcn_s_waitcnt(W_LGKM0);  // OUT writes visible
            SCHEDB();
            BAR();
        }
    } else {
        // ---------------- producer wave: all global traffic ----------------
        const int i = tid - 64;           // lane within wave
        const int ts = i >> 4;            // sub-step 0..3 of a glds op
        const int dq = (i & 15) << 2;     // d quad
        const float* __restrict__ xr_blk = Xr + blkoff;
        const float* __restrict__ xi_blk = Xi + blkoff;
        float* __restrict__ zr_blk = zr + blkoff;
        float* __restrict__ zi_blk = zi + blkoff;

        auto issueglds = [&](int body) {
            const int buf = body & 3;
#pragma unroll
            for (int k = 0; k < NOPS; ++k) {
                const size_t off = (size_t)(body * U + 4 * k + ts) * D + dq;
                // LDS dest: wave-uniform base + lane*16 -> rows 4k..4k+3,
                // exactly matching the per-lane global address (ts, dq).
                __builtin_amdgcn_global_load_lds((gfloat*)(xr_blk + off),
                                                 (lfloat*)&INr[buf][4 * k][0], 16, 0, 0);
                __builtin_amdgcn_global_load_lds((gfloat*)(xi_blk + off),
                                                 (lfloat*)&INi[buf][4 * k][0], 16, 0, 0);
            }
        };
        auto drainbody = [&](int body) {
            const int ob = body & 1;
#pragma unroll
            for (int k = 0; k < NOPS; ++k) {
                const size_t off = (size_t)(body * U + 4 * k + ts) * D + dq;
                const v4f vr = *reinterpret_cast<const v4f*>(&OUTr[ob][4 * k + ts][dq]);
                const v4f vi = *reinterpret_cast<const v4f*>(&OUTi[ob][4 * k + ts][dq]);
                __builtin_nontemporal_store(vr, reinterpret_cast<v4f*>(zr_blk + off));
                __builtin_nontemporal_store(vi, reinterpret_cast<v4f*>(zi_blk + off));
            }
        };

        // prologue: bodies 0,1,2 in flight; ensure body 0 landed (20 newer allowed)
        issueglds(0);
        issueglds(1);
        issueglds(2);
        __builtin_amdgcn_s_waitcnt(W_VM20);
        SCHEDB();
        BAR();

        for (int n = 0; n < NB; ++n) {
            if (n + 3 < NB) issueglds(n + 3);
            SCHEDB();
            if (n + 1 < NB) {
                // wait until loads of body n+1 retired. N = #vmem ops issued
                // after them (FIFO): stores n-3 [n>=3], loads n+2 [n+2<NB],
                // stores n-2 [n>=2], loads n+3 [n+3<NB], 10 each.
                const int after = 10 * ((n >= 3) + (n >= 2) +
                                        (n + 2 < NB) + (n + 3 < NB));
                if (after == 40)      __builtin_amdgcn_s_waitcnt(W_VM40);
                else if (after == 30) __builtin_amdgcn_s_waitcnt(W_VM30);
                else                  __builtin_amdgcn_s_waitcnt(W_VM20);
            }
            SCHEDB();
            if (n >= 1) drainbody(n - 1);   // body n-1 sealed at barrier n-1
            SCHEDB();
            BAR();
        }
        drainbody(NB - 1);                  // sealed at final barrier
    }
}

extern "C" void kernel_launch(void* const* d_in, const int* in_sizes, int n_in,
                              void* d_out, int out_size, void* d_ws, size_t ws_size,
                              hipStream_t stream) {
    const float* Xr = (const float*)d_in[0];
    const float* Xi = (const float*)d_in[1];
    const float* om = (const float*)d_in[2];
    float* zr = (float*)d_out;
    float* zi = zr + (size_t)B * T * D;   // tuple output 2, flat-concatenated

    hopf_scan<<<dim3(B * D / 64), dim3(128), 0, stream>>>(Xr, Xi, om, zr, zi);
}

// Round 8
// 44.436 us; speedup vs baseline: 1.6435x; 1.1160x over previous
//
#include <hip/hip_runtime.h>
#include <hip/hip_bf16.h>

// Hopf oscillator scan: B=32, T=1000, D=512.
// Producer/consumer wave specialization, 256 blocks x 128 threads (2 waves):
//   wave 0 (consumer): pure LDS+VALU recurrence, never touches vmem.
//     R7 fix: reg-burst all 40 body inputs BEFORE the 20-step chain (R6 paid
//     ~120cy ds_read latency per step, 2400cy/body); phi kept in REVOLUTIONS
//     so v_sin/v_cos take it directly (no per-step radian muls).
//   wave 1 (producer): global_load_lds (dwordx4) into 4-deep IN ring,
//     drains OUT (b128 LDS read -> nontemporal x4 store). Unchanged from R6.
// Raw s_barrier per body; producer hand-counted vmcnt(N) (FIFO-simulated).
// Consumer seals OUT with lgkm-only waitcnt (0xC07F).

#define B 32
#define T 1000
#define D 512
#define DTc 0.001f
#define K_IN 0.005f               // INPUT_SCALER * DT
#define KREV 7.95774715e-4f       // INPUT_SCALER * DT / (2*pi)
#define U 20                      // steps per body
#define NB (T / U)                // 50 bodies
#define NOPS (U / 4)              // 5 glds/drain ops per array per body

typedef float v4f __attribute__((ext_vector_type(4)));
typedef const __attribute__((address_space(1))) float gfloat;
typedef __attribute__((address_space(3))) float lfloat;

#define SCHEDB() __builtin_amdgcn_sched_barrier(0)
#define BAR()    __builtin_amdgcn_s_barrier()
// s_waitcnt simm16 (gfx9): [3:0]=vmcnt lo, [6:4]=expcnt, [11:8]=lgkmcnt, [15:14]=vmcnt hi
#define W_LGKM0  0xC07F   // lgkmcnt(0) only
#define W_VM20   0x4F74   // vmcnt(20) only
#define W_VM30   0x4F7E   // vmcnt(30) only
#define W_VM40   0x8F78   // vmcnt(40) only

__global__ __launch_bounds__(128, 1) void hopf_scan(
    const float* __restrict__ Xr, const float* __restrict__ Xi,
    const float* __restrict__ om,
    float* __restrict__ zr, float* __restrict__ zi) {
    const int tid = threadIdx.x;
    const int bb = blockIdx.x;            // 0..255
    const int b = bb >> 3;
    const int dblk = (bb & 7) << 6;       // 64-d block
    const size_t blkoff = (size_t)b * (T * D) + dblk;

    __shared__ __align__(16) float INr[4][U][64];   // 4-deep input ring
    __shared__ __align__(16) float INi[4][U][64];
    __shared__ __align__(16) float OUTr[2][U][64];  // double-buffered output
    __shared__ __align__(16) float OUTi[2][U][64];

    if (tid < 64) {
        // ---------------- consumer wave: LDS + VALU only ----------------
        const int i = tid;
        // rev/step: f_Hz * dt = (om*10 + 0.1) * dt
        const float od = __builtin_fmaf(om[dblk + i], 10.0f, 0.1f) * DTc;
        float r = 1.0f, phi = 0.0f, c = 1.0f, s = 0.0f;  // phi in revolutions

        BAR();                            // body 0 staged by producer
        for (int n = 0; n < NB; ++n) {
            const int ib = n & 3, ob = n & 1;

            float xr[U], xi[U];
#pragma unroll
            for (int t = 0; t < U; ++t) {   // reg-burst: latency pipelines
                xr[t] = INr[ib][t][i];
                xi[t] = INi[ib][t][i];
            }
            SCHEDB();

            float our[U], oui[U];
#pragma unroll
            for (int t = 0; t < U; ++t) {
                const float omr2 = __builtin_fmaf(-r, r, 1.0f);   // 1 - r^2
                r = __builtin_fmaf(omr2 * r, DTc, r);             // + cubic*dt
                r = __builtin_fmaf(K_IN * xr[t], c, r);           // + K*xr*cos
                phi = __builtin_fmaf(-(KREV * xi[t]), s, phi + od);
                s = __builtin_amdgcn_sinf(phi);   // v_sin: input in revs
                c = __builtin_amdgcn_cosf(phi);
                our[t] = r * c;
                oui[t] = r * s;
            }
            SCHEDB();
#pragma unroll
            for (int t = 0; t < U; ++t) {
                OUTr[ob][t][i] = our[t];
                OUTi[ob][t][i] = oui[t];
            }
            __builtin_amdgcn_s_waitcnt(W_LGKM0);  // OUT writes visible
            SCHEDB();
            BAR();
        }
    } else {
        // ---------------- producer wave: all global traffic ----------------
        const int i = tid - 64;           // lane within wave
        const int ts = i >> 4;            // sub-step 0..3 of a glds op
        const int dq = (i & 15) << 2;     // d quad
        const float* __restrict__ xr_blk = Xr + blkoff;
        const float* __restrict__ xi_blk = Xi + blkoff;
        float* __restrict__ zr_blk = zr + blkoff;
        float* __restrict__ zi_blk = zi + blkoff;

        auto issueglds = [&](int body) {
            const int buf = body & 3;
#pragma unroll
            for (int k = 0; k < NOPS; ++k) {
                const size_t off = (size_t)(body * U + 4 * k + ts) * D + dq;
                __builtin_amdgcn_global_load_lds((gfloat*)(xr_blk + off),
                                                 (lfloat*)&INr[buf][4 * k][0], 16, 0, 0);
                __builtin_amdgcn_global_load_lds((gfloat*)(xi_blk + off),
                                                 (lfloat*)&INi[buf][4 * k][0], 16, 0, 0);
            }
        };
        auto drainbody = [&](int body) {
            const int ob = body & 1;
#pragma unroll
            for (int k = 0; k < NOPS; ++k) {
                const size_t off = (size_t)(body * U + 4 * k + ts) * D + dq;
                const v4f vr = *reinterpret_cast<const v4f*>(&OUTr[ob][4 * k + ts][dq]);
                const v4f vi = *reinterpret_cast<const v4f*>(&OUTi[ob][4 * k + ts][dq]);
                __builtin_nontemporal_store(vr, reinterpret_cast<v4f*>(zr_blk + off));
                __builtin_nontemporal_store(vi, reinterpret_cast<v4f*>(zi_blk + off));
            }
        };

        // prologue: bodies 0,1,2 in flight; ensure body 0 landed
        issueglds(0);
        issueglds(1);
        issueglds(2);
        __builtin_amdgcn_s_waitcnt(W_VM20);
        SCHEDB();
        BAR();

        for (int n = 0; n < NB; ++n) {
            if (n + 3 < NB) issueglds(n + 3);
            SCHEDB();
            if (n + 1 < NB) {
                // wait until body n+1's loads retired (FIFO-counted newer ops)
                const int after = 10 * ((n >= 3) + (n >= 2) +
                                        (n + 2 < NB) + (n + 3 < NB));
                if (after == 40)      __builtin_amdgcn_s_waitcnt(W_VM40);
                else if (after == 30) __builtin_amdgcn_s_waitcnt(W_VM30);
                else                  __builtin_amdgcn_s_waitcnt(W_VM20);
            }
            SCHEDB();
            if (n >= 1) drainbody(n - 1);   // body n-1 sealed at barrier n-1
            SCHEDB();
            BAR();
        }
        drainbody(NB - 1);                  // sealed at final barrier
    }
}

extern "C" void kernel_launch(void* const* d_in, const int* in_sizes, int n_in,
                              void* d_out, int out_size, void* d_ws, size_t ws_size,
                              hipStream_t stream) {
    const float* Xr = (const float*)d_in[0];
    const float* Xi = (const float*)d_in[1];
    const float* om = (const float*)d_in[2];
    float* zr = (float*)d_out;
    float* zi = zr + (size_t)B * T * D;   // tuple output 2, flat-concatenated

    hopf_scan<<<dim3(B * D / 64), dim3(128), 0, stream>>>(Xr, Xi, om, zr, zi);
}